// Round 1
// baseline (104.067 us; speedup 1.0000x reference)
//
#include <hip/hip_runtime.h>
#include <hip/hip_bf16.h>

typedef __attribute__((ext_vector_type(4))) float f32x4;
typedef __attribute__((ext_vector_type(8))) short bf16x8;

#define HW    16384   // 128*128
#define CDIM  256

__device__ __forceinline__ unsigned short f2bf(float x) {
    union { float f; unsigned u; } c; c.f = x;
    unsigned r = c.u + 0x7fffu + ((c.u >> 16) & 1u);   // RNE
    return (unsigned short)(r >> 16);
}
__device__ __forceinline__ float bf2f(unsigned short u) {
    union { unsigned u; float f; } c; c.u = ((unsigned)u) << 16;
    return c.f;
}

// LDS tile layout: [row][64 bf16], 128 B per row. XOR-swizzle 16B granules so
// both the m-transposed staging writes and the per-row ds_read_b128 fragment
// reads spread across banks. s(row) = ((row>>2)&3) | ((row&1)<<2), 3 bits.
__device__ __forceinline__ int swz(int row, int k) {
    int G = k >> 3;
    int s = ((row >> 2) & 3) | ((row & 1) << 2);
    return row * 64 + ((G ^ s) << 3) + (k & 7);       // bf16-element index
}

// F2t[b,y,x,c] = sum_k W1[c,k] * features[b,k,y,x]   (bf16 out, channel-last)
// Grid: 1024 blocks x 512 threads. BM=128 pixels, BN=256 (all out-channels), BK=64.
__global__ __launch_bounds__(512, 1) void f2_gemm(
    const float* __restrict__ feat, const float* __restrict__ W1,
    unsigned short* __restrict__ f2t) {
    __shared__ short a_lds[128 * 64];   // 16 KB  (pixels x k)
    __shared__ short b_lds[256 * 64];   // 32 KB  (out-ch  x k)

    const int t      = threadIdx.x;
    const int m_base = blockIdx.x * 128;               // all 128 pixels in one batch
    const float* fb  = feat + (size_t)(m_base >> 14) * CDIM * HW + (m_base & (HW - 1));

    const int lane = t & 63;
    const int wid  = t >> 6;
    const int wm   = wid >> 2;      // 0..1 -> 64-row slab
    const int wn   = wid & 3;       // 0..3 -> 64-col slab

    f32x4 acc[4][4] = {};

    const int sa_m0 = (t & 31) * 4;   // 0..124
    const int sa_k0 = (t >> 5) * 4;   // 0..60

    for (int kk = 0; kk < 4; ++kk) {
        // ---- stage A: 128m x 64k, fp32 -> bf16, transpose in registers ----
        float av[4][4];
#pragma unroll
        for (int dk = 0; dk < 4; ++dk) {
            const float4 v = *reinterpret_cast<const float4*>(
                fb + (size_t)(kk * 64 + sa_k0 + dk) * HW + sa_m0);
            av[dk][0] = v.x; av[dk][1] = v.y; av[dk][2] = v.z; av[dk][3] = v.w;
        }
#pragma unroll
        for (int dm = 0; dm < 4; ++dm) {
            ushort4 w;
            w.x = f2bf(av[0][dm]); w.y = f2bf(av[1][dm]);
            w.z = f2bf(av[2][dm]); w.w = f2bf(av[3][dm]);
            *reinterpret_cast<ushort4*>(&a_lds[swz(sa_m0 + dm, sa_k0)]) = w;
        }
        // ---- stage B: 256n x 64k of W1 (row-major, k contiguous) ----
#pragma unroll
        for (int i = 0; i < 8; ++i) {
            const int e  = t + i * 512;          // 0..4095 float4 tiles
            const int n  = e >> 4;
            const int kq = (e & 15) * 4;
            const float4 v = *reinterpret_cast<const float4*>(
                W1 + (size_t)n * 256 + kk * 64 + kq);
            ushort4 w;
            w.x = f2bf(v.x); w.y = f2bf(v.y); w.z = f2bf(v.z); w.w = f2bf(v.w);
            *reinterpret_cast<ushort4*>(&b_lds[swz(n, kq)]) = w;
        }
        __syncthreads();
        // ---- compute: 2 K-halves of 32, 4x4 fragments of 16x16 per wave ----
#pragma unroll
        for (int ks = 0; ks < 2; ++ks) {
            bf16x8 af[4], bfr[4];
            const int kfrag = ks * 32 + (lane >> 4) * 8;
#pragma unroll
            for (int mi = 0; mi < 4; ++mi) {
                const int row = wm * 64 + mi * 16 + (lane & 15);
                af[mi] = *reinterpret_cast<const bf16x8*>(&a_lds[swz(row, kfrag)]);
            }
#pragma unroll
            for (int ni = 0; ni < 4; ++ni) {
                const int col = wn * 64 + ni * 16 + (lane & 15);
                bfr[ni] = *reinterpret_cast<const bf16x8*>(&b_lds[swz(col, kfrag)]);
            }
#pragma unroll
            for (int mi = 0; mi < 4; ++mi)
#pragma unroll
                for (int ni = 0; ni < 4; ++ni)
                    acc[mi][ni] = __builtin_amdgcn_mfma_f32_16x16x32_bf16(
                        af[mi], bfr[ni], acc[mi][ni], 0, 0, 0);
        }
        __syncthreads();
    }
    // ---- epilogue: D[row][col] -> f2t[(m_base+row)*256 + col] ----
#pragma unroll
    for (int mi = 0; mi < 4; ++mi) {
#pragma unroll
        for (int ni = 0; ni < 4; ++ni) {
            const int col = wn * 64 + ni * 16 + (lane & 15);
#pragma unroll
            for (int r = 0; r < 4; ++r) {
                const int row = wm * 64 + mi * 16 + (lane >> 4) * 4 + r;
                f2t[(size_t)(m_base + row) * 256 + col] = f2bf(acc[mi][ni][r]);
            }
        }
    }
}

// One wave per sample point: bilinear-weighted sum of 4 contiguous 512B rows
// of F2t, then relu(s+b1) . W2 -> 2 scalars, out = batch_edges + d.
__global__ __launch_bounds__(256) void point_kernel(
    const unsigned short* __restrict__ f2t,
    const float* __restrict__ be,      // batch_edges flat (131072 floats)
    const float* __restrict__ b1, const float* __restrict__ W2,
    float* __restrict__ out) {
    const int p    = (blockIdx.x * 256 + threadIdx.x) >> 6;   // 0..65535
    const int lane = threadIdx.x & 63;

    const float ex = be[p * 2 + 0];
    const float ey = be[p * 2 + 1];
    // replicate reference arithmetic (H=W=128)
    const float gx = ex * (2.0f / 128.0f) - 1.0f;
    const float gy = ey * (2.0f / 128.0f) - 1.0f;
    const float px = (gx + 1.0f) * 64.0f - 0.5f;
    const float py = (gy + 1.0f) * 64.0f - 0.5f;
    const float x0f = floorf(px), y0f = floorf(py);
    const int   x0 = (int)x0f, y0 = (int)y0f;
    const float wx1 = px - x0f, wy1 = py - y0f;
    const float wx0 = 1.0f - wx1, wy0 = 1.0f - wy1;

    const size_t pix_base = (size_t)(p >> 13) * HW;   // 8192 points per image
    const int c0 = lane * 4;

    float s0 = 0.f, s1 = 0.f, s2 = 0.f, s3 = 0.f;
#pragma unroll
    for (int cy = 0; cy < 2; ++cy) {
        const int   yi  = y0 + cy;
        const float wy  = cy ? wy1 : wy0;
        const bool  yin = (yi >= 0) && (yi < 128);
        const int   yc  = min(max(yi, 0), 127);
#pragma unroll
        for (int cx = 0; cx < 2; ++cx) {
            const int   xi  = x0 + cx;
            const float wx  = cx ? wx1 : wx0;
            const bool  xin = (xi >= 0) && (xi < 128);
            const int   xc  = min(max(xi, 0), 127);
            const float w   = wx * wy * (float)(xin && yin);
            const ushort4 v = *reinterpret_cast<const ushort4*>(
                &f2t[(pix_base + (size_t)yc * 128 + xc) * 256 + c0]);
            s0 += w * bf2f(v.x); s1 += w * bf2f(v.y);
            s2 += w * bf2f(v.z); s3 += w * bf2f(v.w);
        }
    }
    const float4 bb  = *reinterpret_cast<const float4*>(&b1[c0]);
    const float4 w2a = *reinterpret_cast<const float4*>(&W2[c0]);
    const float4 w2b = *reinterpret_cast<const float4*>(&W2[256 + c0]);
    const float h0 = fmaxf(s0 + bb.x, 0.f);
    const float h1 = fmaxf(s1 + bb.y, 0.f);
    const float h2 = fmaxf(s2 + bb.z, 0.f);
    const float h3 = fmaxf(s3 + bb.w, 0.f);
    float a0 = h0 * w2a.x + h1 * w2a.y + h2 * w2a.z + h3 * w2a.w;
    float a1 = h0 * w2b.x + h1 * w2b.y + h2 * w2b.z + h3 * w2b.w;
#pragma unroll
    for (int off = 32; off > 0; off >>= 1) {
        a0 += __shfl_xor(a0, off);
        a1 += __shfl_xor(a1, off);
    }
    if (lane == 0) {
        out[p * 2 + 0] = ex + a0;
        out[p * 2 + 1] = ey + a1;
    }
}

extern "C" void kernel_launch(void* const* d_in, const int* in_sizes, int n_in,
                              void* d_out, int out_size, void* d_ws, size_t ws_size,
                              hipStream_t stream) {
    const float* feat = (const float*)d_in[0];
    const float* be   = (const float*)d_in[1];
    const float* W1   = (const float*)d_in[2];
    const float* b1   = (const float*)d_in[3];
    const float* W2   = (const float*)d_in[4];
    float* out = (float*)d_out;
    unsigned short* f2t = (unsigned short*)d_ws;   // 131072*256 bf16 = 64 MiB

    f2_gemm<<<1024, 512, 0, stream>>>(feat, W1, f2t);
    point_kernel<<<16384, 256, 0, stream>>>(f2t, be, b1, W2, out);
}

// Round 2
// 87.269 us; speedup vs baseline: 1.1925x; 1.1925x over previous
//
#include <hip/hip_runtime.h>
#include <hip/hip_bf16.h>

typedef __attribute__((ext_vector_type(4))) float f32x4;
typedef __attribute__((ext_vector_type(8))) short bf16x8;

#define HW    16384   // 128*128
#define CDIM  256

__device__ __forceinline__ unsigned short f2bf(float x) {
    union { float f; unsigned u; } c; c.f = x;
    unsigned r = c.u + 0x7fffu + ((c.u >> 16) & 1u);   // RNE
    return (unsigned short)(r >> 16);
}
__device__ __forceinline__ float bf2f(unsigned short u) {
    union { unsigned u; float f; } c; c.u = ((unsigned)u) << 16;
    return c.f;
}

// A/B LDS tile: 128 rows x 64 k bf16, 128B rows.
// byte(row,k) = row*128 + ((k*2) ^ ((row&7)<<4))  -> 2-way max on both
// staging writes (k spread across lanes) and b128 fragment reads.
__device__ __forceinline__ int tswz(int row, int kbyte) {
    return row * 128 + (kbyte ^ ((row & 7) << 4));
}

// F2t[pixel][c] = sum_k W1[c,k] * feat[k][pixel]  (bf16 out, channel-last)
// grid 2048 = 1024 m-tiles x 2 n-halves (n-half major so 2nd feat pass hits L3).
__global__ __launch_bounds__(256, 2) void f2_gemm(
    const float* __restrict__ feat, const float* __restrict__ W1,
    unsigned short* __restrict__ f2t) {
    __shared__ short lds[16384];            // 32KB: A bytes [0,16384), B [16384,32768)
    char* const ldsc = (char*)lds;

    const int t      = threadIdx.x;
    const int m_tile = blockIdx.x & 1023;
    const int n_half = blockIdx.x >> 10;
    const int m_base = m_tile << 7;
    const float* fb  = feat + (size_t)(m_base >> 14) * CDIM * HW + (m_base & (HW - 1));
    const float* wb  = W1 + (size_t)(n_half * 128) * CDIM;

    const int lane = t & 63;
    const int wid  = t >> 6;
    const int wm   = wid >> 1;           // 2 m-slabs of 64
    const int wn   = wid & 1;            // 2 n-slabs of 64

    const int sm0 = (t >> 3) << 2;       // staging row base 0..124 (A:m, B:c)
    const int kb  = (t & 7) << 3;        // staging k base 0..56 (8 k/thread)

    f32x4 acc[4][4] = {};
    float av[8][4];                      // A raw: [dk][dm]
    float bv[4][8];                      // B raw: [dc][dk]

    auto load_tile = [&](int kk) {
        const float* fk = fb + (size_t)(kk * 64 + kb) * HW + sm0;
#pragma unroll
        for (int dk = 0; dk < 8; ++dk) {
            const float4 v = *reinterpret_cast<const float4*>(fk + (size_t)dk * HW);
            av[dk][0] = v.x; av[dk][1] = v.y; av[dk][2] = v.z; av[dk][3] = v.w;
        }
        const float* wk = wb + (size_t)sm0 * CDIM + kk * 64 + kb;
#pragma unroll
        for (int dc = 0; dc < 4; ++dc) {
            const float4 u = *reinterpret_cast<const float4*>(wk + (size_t)dc * CDIM);
            const float4 w = *reinterpret_cast<const float4*>(wk + (size_t)dc * CDIM + 4);
            bv[dc][0] = u.x; bv[dc][1] = u.y; bv[dc][2] = u.z; bv[dc][3] = u.w;
            bv[dc][4] = w.x; bv[dc][5] = w.y; bv[dc][6] = w.z; bv[dc][7] = w.w;
        }
    };

    auto write_tile = [&]() {
#pragma unroll
        for (int dm = 0; dm < 4; ++dm) {           // A: transpose in regs
            const int row = sm0 + dm;
            bf16x8 w;
#pragma unroll
            for (int dk = 0; dk < 8; ++dk) w[dk] = (short)f2bf(av[dk][dm]);
            *reinterpret_cast<bf16x8*>(ldsc + tswz(row, kb * 2)) = w;
        }
#pragma unroll
        for (int dc = 0; dc < 4; ++dc) {           // B: k already contiguous
            const int row = sm0 + dc;
            bf16x8 w;
#pragma unroll
            for (int dk = 0; dk < 8; ++dk) w[dk] = (short)f2bf(bv[dc][dk]);
            *reinterpret_cast<bf16x8*>(ldsc + 16384 + tswz(row, kb * 2)) = w;
        }
    };

    auto compute = [&]() {
#pragma unroll
        for (int ks = 0; ks < 2; ++ks) {
            const int kb2 = ks * 64 + ((lane >> 4) << 4);   // byte offset of k*2
            bf16x8 af[4], bfr[4];
#pragma unroll
            for (int mi = 0; mi < 4; ++mi) {
                const int row = wm * 64 + mi * 16 + (lane & 15);
                af[mi] = *reinterpret_cast<const bf16x8*>(ldsc + tswz(row, kb2));
            }
#pragma unroll
            for (int ni = 0; ni < 4; ++ni) {
                const int c = wn * 64 + ni * 16 + (lane & 15);
                bfr[ni] = *reinterpret_cast<const bf16x8*>(ldsc + 16384 + tswz(c, kb2));
            }
#pragma unroll
            for (int mi = 0; mi < 4; ++mi)
#pragma unroll
                for (int ni = 0; ni < 4; ++ni)
                    acc[mi][ni] = __builtin_amdgcn_mfma_f32_16x16x32_bf16(
                        af[mi], bfr[ni], acc[mi][ni], 0, 0, 0);
        }
    };

    // prologue
    load_tile(0);
    write_tile();
    __syncthreads();
    // main loop: T14 — issue k+1 loads before compute(k), convert/write after
    for (int kk = 0; kk < 4; ++kk) {
        if (kk < 3) load_tile(kk + 1);
        compute();
        __syncthreads();
        if (kk < 3) { write_tile(); __syncthreads(); }
    }

    // ---- epilogue: acc -> bf16 -> LDS (swizzled) -> coalesced dwordx4 stores
    // C-stage layout: byte(row, cb) = row*256 + (cb ^ (((row>>2)&3)<<5))
#pragma unroll
    for (int mi = 0; mi < 4; ++mi)
#pragma unroll
        for (int ni = 0; ni < 4; ++ni) {
            const int c2 = (wn * 64 + ni * 16 + (lane & 15)) * 2;
#pragma unroll
            for (int r = 0; r < 4; ++r) {
                const int row = wm * 64 + mi * 16 + ((lane >> 4) << 2) + r;
                *reinterpret_cast<unsigned short*>(
                    ldsc + row * 256 + (c2 ^ (((row >> 2) & 3) << 5))) =
                    f2bf(acc[mi][ni][r]);
            }
        }
    __syncthreads();
#pragma unroll
    for (int i = 0; i < 8; ++i) {
        const int row = ((t >> 4) << 3) + i;
        const int cb  = (t & 15) * 16;
        const int4 v = *reinterpret_cast<const int4*>(
            ldsc + row * 256 + (cb ^ (((row >> 2) & 3) << 5)));
        *reinterpret_cast<int4*>((char*)f2t +
            (size_t)(m_base + row) * 512 + n_half * 256 + cb) = v;
    }
}

// One wave per sample point: bilinear-weighted sum of 4 contiguous 512B rows
// of F2t, then relu(s+b1) . W2 -> 2 scalars, out = batch_edges + d.
__global__ __launch_bounds__(256) void point_kernel(
    const unsigned short* __restrict__ f2t,
    const float* __restrict__ be,
    const float* __restrict__ b1, const float* __restrict__ W2,
    float* __restrict__ out) {
    const int p    = (blockIdx.x * 256 + threadIdx.x) >> 6;   // 0..65535
    const int lane = threadIdx.x & 63;

    const float ex = be[p * 2 + 0];
    const float ey = be[p * 2 + 1];
    const float gx = ex * (2.0f / 128.0f) - 1.0f;
    const float gy = ey * (2.0f / 128.0f) - 1.0f;
    const float px = (gx + 1.0f) * 64.0f - 0.5f;
    const float py = (gy + 1.0f) * 64.0f - 0.5f;
    const float x0f = floorf(px), y0f = floorf(py);
    const int   x0 = (int)x0f, y0 = (int)y0f;
    const float wx1 = px - x0f, wy1 = py - y0f;
    const float wx0 = 1.0f - wx1, wy0 = 1.0f - wy1;

    const size_t pix_base = (size_t)(p >> 13) * HW;
    const int c0 = lane * 4;

    float s0 = 0.f, s1 = 0.f, s2 = 0.f, s3 = 0.f;
#pragma unroll
    for (int cy = 0; cy < 2; ++cy) {
        const int   yi  = y0 + cy;
        const float wy  = cy ? wy1 : wy0;
        const bool  yin = (yi >= 0) && (yi < 128);
        const int   yc  = min(max(yi, 0), 127);
#pragma unroll
        for (int cx = 0; cx < 2; ++cx) {
            const int   xi  = x0 + cx;
            const float wx  = cx ? wx1 : wx0;
            const bool  xin = (xi >= 0) && (xi < 128);
            const int   xc  = min(max(xi, 0), 127);
            const float w   = wx * wy * (float)(xin && yin);
            const ushort4 v = *reinterpret_cast<const ushort4*>(
                &f2t[(pix_base + (size_t)yc * 128 + xc) * 256 + c0]);
            s0 += w * bf2f(v.x); s1 += w * bf2f(v.y);
            s2 += w * bf2f(v.z); s3 += w * bf2f(v.w);
        }
    }
    const float4 bb  = *reinterpret_cast<const float4*>(&b1[c0]);
    const float4 w2a = *reinterpret_cast<const float4*>(&W2[c0]);
    const float4 w2b = *reinterpret_cast<const float4*>(&W2[256 + c0]);
    const float h0 = fmaxf(s0 + bb.x, 0.f);
    const float h1 = fmaxf(s1 + bb.y, 0.f);
    const float h2 = fmaxf(s2 + bb.z, 0.f);
    const float h3 = fmaxf(s3 + bb.w, 0.f);
    float a0 = h0 * w2a.x + h1 * w2a.y + h2 * w2a.z + h3 * w2a.w;
    float a1 = h0 * w2b.x + h1 * w2b.y + h2 * w2b.z + h3 * w2b.w;
#pragma unroll
    for (int off = 32; off > 0; off >>= 1) {
        a0 += __shfl_xor(a0, off);
        a1 += __shfl_xor(a1, off);
    }
    if (lane == 0) {
        out[p * 2 + 0] = ex + a0;
        out[p * 2 + 1] = ey + a1;
    }
}

extern "C" void kernel_launch(void* const* d_in, const int* in_sizes, int n_in,
                              void* d_out, int out_size, void* d_ws, size_t ws_size,
                              hipStream_t stream) {
    const float* feat = (const float*)d_in[0];
    const float* be   = (const float*)d_in[1];
    const float* W1   = (const float*)d_in[2];
    const float* b1   = (const float*)d_in[3];
    const float* W2   = (const float*)d_in[4];
    float* out = (float*)d_out;
    unsigned short* f2t = (unsigned short*)d_ws;   // 131072*256 bf16 = 64 MiB

    f2_gemm<<<2048, 256, 0, stream>>>(feat, W1, f2t);
    point_kernel<<<16384, 256, 0, stream>>>(f2t, be, b1, W2, out);
}